// Round 12
// baseline (209.372 us; speedup 1.0000x reference)
//
#include <hip/hip_runtime.h>

using u16 = unsigned short;
using u32 = unsigned int;
using u64 = unsigned long long;

#define ALPHA 0.2f
#define LOG2E 1.4426950408889634f

typedef __bf16 bf16x8 __attribute__((ext_vector_type(8)));
typedef float f32x4 __attribute__((ext_vector_type(4)));
typedef float f32x16 __attribute__((ext_vector_type(16)));

__device__ __forceinline__ u16 f2bf(float f) {
  u32 u = __builtin_bit_cast(u32, f);
  u += 0x7FFFu + ((u >> 16) & 1u);   // RTNE
  return (u16)(u >> 16);
}
__device__ __forceinline__ float bf2f(u16 h) {
  u32 u = ((u32)h) << 16;
  return __builtin_bit_cast(float, u);
}
__device__ __forceinline__ void gload_lds16(const void* g, void* l) {
  __builtin_amdgcn_global_load_lds((__attribute__((address_space(1))) void*)g,
                                   (__attribute__((address_space(3))) void*)l,
                                   16, 0, 0);
}

// ---------- cast+transpose W: wbt[n][k] = bf16(W[k][n]) ----------
__global__ __launch_bounds__(256) void k_cast_wT(const float* __restrict__ W, u16* __restrict__ wbt) {
  int idx = blockIdx.x * 256 + threadIdx.x;
  int k = idx >> 9, n = idx & 511;
  wbt[n * 512 + k] = f2bf(W[idx]);
}

// ---------- gemm1: h = x@W (M=16384,K=512,N=512). 128x128 tile, 4 waves.
// Triple-buffered, counted vmcnt, XCD-swizzled. Epilogue: hbf + score partials.
__global__ __launch_bounds__(256, 2) void k_gemm1(const float* __restrict__ x, const u16* __restrict__ wbt,
                                                  const float* __restrict__ a,
                                                  u16* __restrict__ hbf,
                                                  float* __restrict__ s1p, float* __restrict__ s2p) {
  __shared__ __attribute__((aligned(16))) char lds[73728];
  __shared__ __attribute__((aligned(16))) float a_l[256];

  const int t = threadIdx.x;
  const int lane = t & 63;
  const int w = t >> 6;
  const int l31 = lane & 31, lhi = lane >> 5;
  const int rb = w >> 1, cg = w & 1;
  const int g = blockIdx.x;
  const int cb = (g >> 3) & 3;
  const int tile_m = (g & 7) | ((g >> 5) << 3);
  const int row0 = tile_m * 128;
  const int col0 = cb * 128;

  a_l[t] = (t < 128) ? a[col0 + t] : a[512 + col0 + (t - 128)];

  f32x16 acc[2][2];
#pragma unroll
  for (int i = 0; i < 2; ++i)
#pragma unroll
    for (int j = 0; j < 2; ++j)
#pragma unroll
      for (int r = 0; r < 16; ++r) acc[i][j][r] = 0.f;

#define STAGE_G1(kt, Ab, Bb)                                                              \
  {                                                                                       \
    const int k0_ = (kt) * 32;                                                            \
    _Pragma("unroll")                                                                     \
    for (int i = 0; i < 4; ++i) {                                                         \
      int G = i * 256 + t;                                                                \
      int row = G >> 3, ks = G & 7;                                                       \
      gload_lds16(x + (size_t)(row0 + row) * 512 + k0_ + ((ks ^ (row & 7)) * 4),          \
                  (Ab) + (size_t)(i * 256 + w * 64) * 16);                                \
    }                                                                                     \
    _Pragma("unroll")                                                                     \
    for (int i = 0; i < 2; ++i) {                                                         \
      int G = i * 256 + t;                                                                \
      int col = G >> 2, ks = G & 3;                                                       \
      gload_lds16(wbt + (size_t)(col0 + col) * 512 + k0_ + ((ks ^ ((col >> 1) & 3)) * 8), \
                  (Bb) + (size_t)(i * 256 + w * 64) * 16);                                \
    }                                                                                     \
  }

#define COMPUTE_G1(Ab, Bb)                                                                         \
  {                                                                                                \
    _Pragma("unroll")                                                                              \
    for (int ks = 0; ks < 2; ++ks) {                                                               \
      bf16x8 af[2];                                                                                \
      _Pragma("unroll")                                                                            \
      for (int sub = 0; sub < 2; ++sub) {                                                          \
        const int arow = rb * 64 + sub * 32 + l31;                                                 \
        const int kg = ks * 4 + lhi * 2;                                                           \
        f32x4 fa0 = *reinterpret_cast<const f32x4*>((Ab) + (size_t)(arow * 8 + (kg ^ (arow & 7))) * 16); \
        f32x4 fa1 = *reinterpret_cast<const f32x4*>((Ab) + (size_t)(arow * 8 + ((kg + 1) ^ (arow & 7))) * 16); \
        _Pragma("unroll")                                                                          \
        for (int jj = 0; jj < 4; ++jj) {                                                           \
          af[sub][jj] = (__bf16)fa0[jj];                                                           \
          af[sub][jj + 4] = (__bf16)fa1[jj];                                                       \
        }                                                                                          \
      }                                                                                            \
      bf16x8 bfr[2];                                                                               \
      _Pragma("unroll")                                                                            \
      for (int bt = 0; bt < 2; ++bt) {                                                             \
        const int bcol = cg * 64 + bt * 32 + l31;                                                  \
        const int kslot = (ks * 2 + lhi) ^ ((bcol >> 1) & 3);                                      \
        bfr[bt] = *reinterpret_cast<const bf16x8*>((Bb) + (size_t)(bcol * 4 + kslot) * 16);        \
      }                                                                                            \
      _Pragma("unroll")                                                                            \
      for (int sub = 0; sub < 2; ++sub)                                                            \
        _Pragma("unroll")                                                                          \
        for (int bt = 0; bt < 2; ++bt)                                                             \
          acc[sub][bt] = __builtin_amdgcn_mfma_f32_32x32x16_bf16(af[sub], bfr[bt], acc[sub][bt], 0, 0, 0); \
    }                                                                                              \
  }

  char* Ac = lds;             char* Bc = lds + 49152;
  char* An = lds + 16384;     char* Bn = lds + 57344;
  char* As = lds + 32768;     char* Bs = lds + 65536;

  STAGE_G1(0, Ac, Bc);
  STAGE_G1(1, An, Bn);
  __builtin_amdgcn_sched_barrier(0);
  asm volatile("s_waitcnt vmcnt(6) lgkmcnt(0)" ::: "memory");
  __builtin_amdgcn_s_barrier();
  __builtin_amdgcn_sched_barrier(0);

#pragma unroll 1
  for (int kt = 0; kt < 14; ++kt) {
    STAGE_G1(kt + 2, As, Bs);
    COMPUTE_G1(Ac, Bc);
    __builtin_amdgcn_sched_barrier(0);
    asm volatile("s_waitcnt vmcnt(6)" ::: "memory");
    __builtin_amdgcn_s_barrier();
    __builtin_amdgcn_sched_barrier(0);
    char* ta = Ac; Ac = An; An = As; As = ta;
    char* tb = Bc; Bc = Bn; Bn = Bs; Bs = tb;
  }
  COMPUTE_G1(Ac, Bc);
  __builtin_amdgcn_sched_barrier(0);
  asm volatile("s_waitcnt vmcnt(0)" ::: "memory");
  __builtin_amdgcn_s_barrier();
  __builtin_amdgcn_sched_barrier(0);
  COMPUTE_G1(An, Bn);
#undef STAGE_G1
#undef COMPUTE_G1

  __syncthreads();

  u16* lT = (u16*)lds;
#pragma unroll
  for (int sub = 0; sub < 2; ++sub)
#pragma unroll
    for (int bt = 0; bt < 2; ++bt) {
      const int col = cg * 64 + bt * 32 + l31;
#pragma unroll
      for (int r = 0; r < 16; ++r) {
        int row = rb * 64 + sub * 32 + (r & 3) + 8 * (r >> 2) + 4 * lhi;
        lT[row * 136 + col] = f2bf(acc[sub][bt][r]);
      }
    }
  __syncthreads();

#pragma unroll
  for (int i = 0; i < 8; ++i) {
    int G = i * 256 + t;
    int row = G >> 4, gg = G & 15;
    uint4 v = *reinterpret_cast<const uint4*>(&lT[row * 136 + gg * 8]);
    *reinterpret_cast<uint4*>(&hbf[(size_t)(row0 + row) * 512 + col0 + gg * 8]) = v;
  }
  {
    const int r2 = t >> 1, half = t & 1;
    float d1 = 0.f, d2 = 0.f;
#pragma unroll
    for (int i = 0; i < 8; ++i) {
      uint4 v = *reinterpret_cast<const uint4*>(&lT[r2 * 136 + half * 64 + i * 8]);
      u32 wds[4] = {v.x, v.y, v.z, v.w};
#pragma unroll
      for (int jj = 0; jj < 8; ++jj) {
        float h = bf2f((u16)(wds[jj >> 1] >> ((jj & 1) * 16)));
        d1 += h * a_l[half * 64 + i * 8 + jj];
        d2 += h * a_l[128 + half * 64 + i * 8 + jj];
      }
    }
    d1 += __shfl_xor(d1, 1);
    d2 += __shfl_xor(d2, 1);
    if (half == 0) {
      s1p[cb * 16384 + row0 + r2] = d1;
      s2p[cb * 16384 + row0 + r2] = d2;
    }
  }
}

// ---------- reduce score partials -> s1L, s2L (scaled by log2e) ----------
__global__ __launch_bounds__(256) void k_reduce(const float* __restrict__ s1p, const float* __restrict__ s2p,
                                                float* __restrict__ s1L, float* __restrict__ s2L) {
  int id = blockIdx.x * 256 + threadIdx.x;
  float d1 = s1p[id] + s1p[16384 + id] + s1p[32768 + id] + s1p[49152 + id];
  float d2 = s2p[id] + s2p[16384 + id] + s2p[32768 + id] + s2p[49152 + id];
  s1L[id] = d1 * LOG2E;
  s2L[id] = d2 * LOG2E;
}

// ---------- prep: per batch, sort s2L; E1/E2 tables; exact scalar scans -> invd;
// k_n per row; rows sorted by k_n -> krows. ----------
__global__ __launch_bounds__(1024) void k_prep(const float* __restrict__ s1Lg, const float* __restrict__ s2Lg,
                                               float* __restrict__ e1s, float* __restrict__ e2s,
                                               u32* __restrict__ permM, u32* __restrict__ krows,
                                               float* __restrict__ invd) {
  __shared__ u64 sk[1024];
  __shared__ float s2sv[1024];
  __shared__ float arrA[1024];   // incl prefix scan of E2
  __shared__ float arrB[1024];   // incl scan of reversed E1 (suffix sums)
  const int b = blockIdx.x;
  const int t = threadIdx.x;

  // sort (s2L, idx) ascending via sortable-u32 key
  {
    float v = s2Lg[b * 1024 + t];
    u32 bits = __builtin_bit_cast(u32, v);
    u32 key = (bits & 0x80000000u) ? ~bits : (bits | 0x80000000u);
    sk[t] = ((u64)key << 32) | (u32)t;
  }
  for (int size = 2; size <= 1024; size <<= 1)
    for (int stride = size >> 1; stride > 0; stride >>= 1) {
      __syncthreads();
      int ixj = t ^ stride;
      if (ixj > t) {
        u64 va = sk[t], vb = sk[ixj];
        bool asc = ((t & size) == 0);
        if ((va > vb) == asc) { sk[t] = vb; sk[ixj] = va; }
      }
    }
  __syncthreads();

  const u32 idx = (u32)(sk[t] & 1023u);
  const float sv = s2Lg[b * 1024 + idx];
  s2sv[t] = sv;
  __syncthreads();

  const float E1 = exp2f(sv), E2 = exp2f(ALPHA * sv);
  e1s[b * 1024 + t] = E1;
  e2s[b * 1024 + t] = E2;
  permM[b * 1024 + t] = idx;
  arrA[t] = E2;
  arrB[t] = exp2f(s2sv[1023 - t]);   // E1 at reversed position
  __syncthreads();

  for (int off = 1; off < 1024; off <<= 1) {
    float aA = (t >= off) ? arrA[t - off] : 0.f;
    float aB = (t >= off) ? arrB[t - off] : 0.f;
    __syncthreads();
    arrA[t] += aA;
    arrB[t] += aB;
    __syncthreads();
  }

  // per row n = t: k_n and denominator
  int kn;
  {
    const float s1v = s1Lg[b * 1024 + t];
    const float thr = -s1v;
    int lo = 0, hi = 1024;
    while (lo < hi) { int mid = (lo + hi) >> 1; if (s2sv[mid] <= thr) lo = mid + 1; else hi = mid; }
    kn = lo;   // #{i: s2s[i] <= thr}
    float se1suf = (kn == 1024) ? 0.f : arrB[1023 - kn];   // sum_{i>=kn} E1
    float se2pre = (kn == 0) ? 0.f : arrA[kn - 1];          // sum_{i<kn} E2
    float den = exp2f(s1v) * se1suf + exp2f(ALPHA * s1v) * se2pre;
    invd[b * 1024 + t] = 1.0f / den;
  }

  // sort rows by kn ascending: key = (kn<<10)|n  (kn<=1024 fits 11 bits)
  u32* sk32 = (u32*)sk;
  __syncthreads();
  sk32[t] = ((u32)kn << 10) | (u32)t;
  for (int size = 2; size <= 1024; size <<= 1)
    for (int stride = size >> 1; stride > 0; stride >>= 1) {
      __syncthreads();
      int ixj = t ^ stride;
      if (ixj > t) {
        u32 va = sk32[t], vb = sk32[ixj];
        bool asc = ((t & size) == 0);
        if ((va > vb) == asc) { sk32[t] = vb; sk32[ixj] = va; }
      }
    }
  __syncthreads();
  krows[b * 1024 + t] = sk32[t];
}

// ---------- sweep: per (batch, 64-f chunk, n-quarter): backward suffix walk over
// sorted m; at each row's k_n store bf16 (S1suf, S2pre) pair into tab. ----------
__global__ __launch_bounds__(256, 2) void k_sweep(const u16* __restrict__ hbf,
                                                  const float* __restrict__ e1s, const float* __restrict__ e2s,
                                                  const u32* __restrict__ permM, const u32* __restrict__ krows,
                                                  u32* __restrict__ tab) {
  __shared__ u32 krows_l[1024];
  __shared__ float e1_l[1024];
  __shared__ float e2_l[1024];
  __shared__ u32 perm_l[1024];
  __shared__ float T1[4][64];
  __shared__ float T2[4][64];

  const int t = threadIdx.x;
  const int lane = t & 63;
  const int mg = t >> 6;                  // wave = m-chunk of 256 sorted positions
  const int B = blockIdx.x;
  const int b = (B & 7) * 2 + ((B >> 3) & 1);   // XCD swizzle (matches k_final)
  const int j2 = B >> 4;                  // 0..31
  const int fc = j2 >> 2;                 // 0..7 : 64-f chunk
  const int nq = j2 & 3;                  // 0..3 : quarter of krows positions
  const int nhLo = nq * 256, nhHi = nhLo + 256;
  const int fcol = fc * 64 + lane;

#pragma unroll
  for (int q = 0; q < 4; ++q) {
    int i = q * 256 + t;
    krows_l[i] = krows[b * 1024 + i];
    e1_l[i] = e1s[b * 1024 + i];
    e2_l[i] = e2s[b * 1024 + i];
    perm_l[i] = permM[b * 1024 + i];
  }
  __syncthreads();

  const int lo = mg * 256;
  // phase A: chunk totals
  float t1 = 0.f, t2 = 0.f;
#pragma unroll 2
  for (int ii = 0; ii < 256; ++ii) {
    int i = lo + ii;
    float hv = bf2f(hbf[(size_t)(b * 1024 + perm_l[i]) * 512 + fcol]);
    t1 = fmaf(e1_l[i], hv, t1);
    t2 = fmaf(e2_l[i], hv, t2);
  }
  T1[mg][lane] = t1;
  T2[mg][lane] = t2;
  __syncthreads();

  float base1 = 0.f, base2 = 0.f, tot2 = 0.f;
#pragma unroll
  for (int m2 = 0; m2 < 4; ++m2) {
    float v2 = T2[m2][lane];
    tot2 += v2;
    if (m2 > mg) { base1 += T1[m2][lane]; base2 += v2; }
  }

  // ptr = first index with kn > hi+1, clamped to this block's position range
  int ptr;
  {
    const int kin = lo + 256;   // hi+1
    int l2 = 0, h2 = 1024;
    while (l2 < h2) { int mid = (l2 + h2) >> 1; if ((int)(krows_l[mid] >> 10) <= kin) l2 = mid + 1; else h2 = mid; }
    ptr = l2 < nhHi ? l2 : nhHi;
  }

  // phase B: backward walk, emitting before adding element i (suffix from i+1)
  float acc1 = base1, acc2 = base2;
  u32* tabb = tab + (size_t)b * 1024 * 512 + fcol;
#pragma unroll 1
  for (int ii = 255; ii >= 0; --ii) {
    const int i = lo + ii;
    const int k = i + 1;
    while (ptr > nhLo) {
      u32 v = krows_l[ptr - 1];
      if ((int)(v >> 10) != k) break;
      u32 pk = (u32)f2bf(acc1) | ((u32)f2bf(tot2 - acc2) << 16);
      tabb[(size_t)(ptr - 1) * 512] = pk;
      --ptr;
    }
    float hv = bf2f(hbf[(size_t)(b * 1024 + perm_l[i]) * 512 + fcol]);
    acc1 = fmaf(e1_l[i], hv, acc1);
    acc2 = fmaf(e2_l[i], hv, acc2);
  }
  if (mg == 0) {
    while (ptr > nhLo && (krows_l[ptr - 1] >> 10) == 0) {
      u32 pk = (u32)f2bf(acc1) | ((u32)f2bf(tot2 - acc2) << 16);
      tabb[(size_t)(ptr - 1) * 512] = pk;
      --ptr;
    }
  }
}

// ---------- final: per row j: out[n] = elu((c1*A + c2*B)*inv + beta*h[n]) ----------
__global__ __launch_bounds__(256) void k_final(const u32* __restrict__ tab, const u32* __restrict__ krows,
                                               const float* __restrict__ s1Lg, const float* __restrict__ invd,
                                               const u16* __restrict__ hbf, const float* __restrict__ betag,
                                               float* __restrict__ out) {
  const int t = threadIdx.x;
  const int lane = t & 63;
  const int w = t >> 6;
  const int gid = blockIdx.x;
  const int b = (gid & 7) * 2 + ((gid >> 3) & 1);   // same XCD mapping as k_sweep
  const int rg = gid >> 4;                           // 0..255
  const int j = rg * 4 + w;

  const u32 kr = krows[b * 1024 + j];
  const int n = kr & 1023;
  const float s1v = s1Lg[b * 1024 + n];
  const float c1 = exp2f(s1v), c2 = exp2f(ALPHA * s1v);
  const float inv = invd[b * 1024 + n];
  const float beta = betag[0];

  const u32* trow = tab + ((size_t)b * 1024 + j) * 512 + lane * 8;
  uint4 ta = reinterpret_cast<const uint4*>(trow)[0];
  uint4 tb2 = reinterpret_cast<const uint4*>(trow)[1];
  uint4 hv4 = *reinterpret_cast<const uint4*>(hbf + ((size_t)b * 1024 + n) * 512 + lane * 8);

  u32 tw[8] = {ta.x, ta.y, ta.z, ta.w, tb2.x, tb2.y, tb2.z, tb2.w};
  u32 hw[4] = {hv4.x, hv4.y, hv4.z, hv4.w};
  float res[8];
#pragma unroll
  for (int q = 0; q < 8; ++q) {
    float A = bf2f((u16)(tw[q] & 0xFFFFu));
    float Bv = bf2f((u16)(tw[q] >> 16));
    float hvf = bf2f((u16)(hw[q >> 1] >> ((q & 1) * 16)));
    float xv = (c1 * A + c2 * Bv) * inv + beta * hvf;
    res[q] = xv > 0.f ? xv : __expf(xv) - 1.0f;
  }
  float* op = out + ((size_t)b * 1024 + n) * 512 + lane * 8;
  reinterpret_cast<float4*>(op)[0] = make_float4(res[0], res[1], res[2], res[3]);
  reinterpret_cast<float4*>(op)[1] = make_float4(res[4], res[5], res[6], res[7]);
}

extern "C" void kernel_launch(void* const* d_in, const int* in_sizes, int n_in,
                              void* d_out, int out_size, void* d_ws, size_t ws_size,
                              hipStream_t stream) {
  const float* x = (const float*)d_in[0];
  const float* W = (const float*)d_in[1];
  const float* a = (const float*)d_in[2];
  const float* beta = (const float*)d_in[3];
  float* out = (float*)d_out;

  char* ws = (char*)d_ws;
  u16* hbf = (u16*)ws;                                   // [0, 16M)
  u32* tab = (u32*)(ws + (16u << 20));                   // [16M, 48M+1.5M): 33.5 MB
  char* sm = ws + (50u << 20);                           // small arrays @50M
  float* e1s = (float*)(sm);                             // 64 KB
  float* e2s = (float*)(sm + (64u << 10));
  u32* permM = (u32*)(sm + (128u << 10));
  u32* krows = (u32*)(sm + (192u << 10));
  float* invd = (float*)(sm + (256u << 10));
  float* s1L = (float*)(sm + (320u << 10));
  float* s2L = (float*)(sm + (384u << 10));
  float* s1p = (float*)(sm + (448u << 10));              // 256 KB
  float* s2p = (float*)(sm + (704u << 10));              // 256 KB
  u16* wbt = (u16*)(ws + (51u << 20));                   // 512 KB

  k_cast_wT<<<1024, 256, 0, stream>>>(W, wbt);
  k_gemm1<<<512, 256, 0, stream>>>(x, wbt, a, hbf, s1p, s2p);
  k_reduce<<<64, 256, 0, stream>>>(s1p, s2p, s1L, s2L);
  k_prep<<<16, 1024, 0, stream>>>(s1L, s2L, e1s, e2s, permM, krows, invd);
  k_sweep<<<512, 256, 0, stream>>>(hbf, e1s, e2s, permM, krows, tab);
  k_final<<<4096, 256, 0, stream>>>(tab, krows, s1L, invd, hbf, beta, out);
}

// Round 13
// 129.387 us; speedup vs baseline: 1.6182x; 1.6182x over previous
//
#include <hip/hip_runtime.h>

using u16 = unsigned short;
using u32 = unsigned int;
using u64 = unsigned long long;

#define ALPHA 0.2f
#define LOG2E 1.4426950408889634f

typedef __bf16 bf16x8 __attribute__((ext_vector_type(8)));
typedef float f32x4 __attribute__((ext_vector_type(4)));
typedef float f32x16 __attribute__((ext_vector_type(16)));

__device__ __forceinline__ u16 f2bf(float f) {
  u32 u = __builtin_bit_cast(u32, f);
  u += 0x7FFFu + ((u >> 16) & 1u);   // RTNE
  return (u16)(u >> 16);
}
__device__ __forceinline__ float bf2f(u16 h) {
  u32 u = ((u32)h) << 16;
  return __builtin_bit_cast(float, u);
}
__device__ __forceinline__ void gload_lds16(const void* g, void* l) {
  __builtin_amdgcn_global_load_lds((__attribute__((address_space(1))) void*)g,
                                   (__attribute__((address_space(3))) void*)l,
                                   16, 0, 0);
}

// ---------- cast+transpose W: wbt[n][k] = bf16(W[k][n]) ----------
__global__ __launch_bounds__(256) void k_cast_wT(const float* __restrict__ W, u16* __restrict__ wbt) {
  int idx = blockIdx.x * 256 + threadIdx.x;
  int k = idx >> 9, n = idx & 511;
  wbt[n * 512 + k] = f2bf(W[idx]);
}

// ---------- gemm1: h = x@W (M=16384,K=512,N=512). 128x128 tile, 4 waves.
// Triple-buffered, counted vmcnt, XCD-swizzled. Epilogue: hbf + score partials.
__global__ __launch_bounds__(256, 2) void k_gemm1(const float* __restrict__ x, const u16* __restrict__ wbt,
                                                  const float* __restrict__ a,
                                                  u16* __restrict__ hbf,
                                                  float* __restrict__ s1p, float* __restrict__ s2p) {
  __shared__ __attribute__((aligned(16))) char lds[73728];
  __shared__ __attribute__((aligned(16))) float a_l[256];

  const int t = threadIdx.x;
  const int lane = t & 63;
  const int w = t >> 6;
  const int l31 = lane & 31, lhi = lane >> 5;
  const int rb = w >> 1, cg = w & 1;
  const int g = blockIdx.x;
  const int cb = (g >> 3) & 3;
  const int tile_m = (g & 7) | ((g >> 5) << 3);
  const int row0 = tile_m * 128;
  const int col0 = cb * 128;

  a_l[t] = (t < 128) ? a[col0 + t] : a[512 + col0 + (t - 128)];

  f32x16 acc[2][2];
#pragma unroll
  for (int i = 0; i < 2; ++i)
#pragma unroll
    for (int j = 0; j < 2; ++j)
#pragma unroll
      for (int r = 0; r < 16; ++r) acc[i][j][r] = 0.f;

#define STAGE_G1(kt, Ab, Bb)                                                              \
  {                                                                                       \
    const int k0_ = (kt) * 32;                                                            \
    _Pragma("unroll")                                                                     \
    for (int i = 0; i < 4; ++i) {                                                         \
      int G = i * 256 + t;                                                                \
      int row = G >> 3, ks = G & 7;                                                       \
      gload_lds16(x + (size_t)(row0 + row) * 512 + k0_ + ((ks ^ (row & 7)) * 4),          \
                  (Ab) + (size_t)(i * 256 + w * 64) * 16);                                \
    }                                                                                     \
    _Pragma("unroll")                                                                     \
    for (int i = 0; i < 2; ++i) {                                                         \
      int G = i * 256 + t;                                                                \
      int col = G >> 2, ks = G & 3;                                                       \
      gload_lds16(wbt + (size_t)(col0 + col) * 512 + k0_ + ((ks ^ ((col >> 1) & 3)) * 8), \
                  (Bb) + (size_t)(i * 256 + w * 64) * 16);                                \
    }                                                                                     \
  }

#define COMPUTE_G1(Ab, Bb)                                                                         \
  {                                                                                                \
    _Pragma("unroll")                                                                              \
    for (int ks = 0; ks < 2; ++ks) {                                                               \
      bf16x8 af[2];                                                                                \
      _Pragma("unroll")                                                                            \
      for (int sub = 0; sub < 2; ++sub) {                                                          \
        const int arow = rb * 64 + sub * 32 + l31;                                                 \
        const int kg = ks * 4 + lhi * 2;                                                           \
        f32x4 fa0 = *reinterpret_cast<const f32x4*>((Ab) + (size_t)(arow * 8 + (kg ^ (arow & 7))) * 16); \
        f32x4 fa1 = *reinterpret_cast<const f32x4*>((Ab) + (size_t)(arow * 8 + ((kg + 1) ^ (arow & 7))) * 16); \
        _Pragma("unroll")                                                                          \
        for (int jj = 0; jj < 4; ++jj) {                                                           \
          af[sub][jj] = (__bf16)fa0[jj];                                                           \
          af[sub][jj + 4] = (__bf16)fa1[jj];                                                       \
        }                                                                                          \
      }                                                                                            \
      bf16x8 bfr[2];                                                                               \
      _Pragma("unroll")                                                                            \
      for (int bt = 0; bt < 2; ++bt) {                                                             \
        const int bcol = cg * 64 + bt * 32 + l31;                                                  \
        const int kslot = (ks * 2 + lhi) ^ ((bcol >> 1) & 3);                                      \
        bfr[bt] = *reinterpret_cast<const bf16x8*>((Bb) + (size_t)(bcol * 4 + kslot) * 16);        \
      }                                                                                            \
      _Pragma("unroll")                                                                            \
      for (int sub = 0; sub < 2; ++sub)                                                            \
        _Pragma("unroll")                                                                          \
        for (int bt = 0; bt < 2; ++bt)                                                             \
          acc[sub][bt] = __builtin_amdgcn_mfma_f32_32x32x16_bf16(af[sub], bfr[bt], acc[sub][bt], 0, 0, 0); \
    }                                                                                              \
  }

  char* Ac = lds;             char* Bc = lds + 49152;
  char* An = lds + 16384;     char* Bn = lds + 57344;
  char* As = lds + 32768;     char* Bs = lds + 65536;

  STAGE_G1(0, Ac, Bc);
  STAGE_G1(1, An, Bn);
  __builtin_amdgcn_sched_barrier(0);
  asm volatile("s_waitcnt vmcnt(6) lgkmcnt(0)" ::: "memory");
  __builtin_amdgcn_s_barrier();
  __builtin_amdgcn_sched_barrier(0);

#pragma unroll 1
  for (int kt = 0; kt < 14; ++kt) {
    STAGE_G1(kt + 2, As, Bs);
    COMPUTE_G1(Ac, Bc);
    __builtin_amdgcn_sched_barrier(0);
    asm volatile("s_waitcnt vmcnt(6)" ::: "memory");
    __builtin_amdgcn_s_barrier();
    __builtin_amdgcn_sched_barrier(0);
    char* ta = Ac; Ac = An; An = As; As = ta;
    char* tb = Bc; Bc = Bn; Bn = Bs; Bs = tb;
  }
  COMPUTE_G1(Ac, Bc);
  __builtin_amdgcn_sched_barrier(0);
  asm volatile("s_waitcnt vmcnt(0)" ::: "memory");
  __builtin_amdgcn_s_barrier();
  __builtin_amdgcn_sched_barrier(0);
  COMPUTE_G1(An, Bn);
#undef STAGE_G1
#undef COMPUTE_G1

  __syncthreads();

  u16* lT = (u16*)lds;
#pragma unroll
  for (int sub = 0; sub < 2; ++sub)
#pragma unroll
    for (int bt = 0; bt < 2; ++bt) {
      const int col = cg * 64 + bt * 32 + l31;
#pragma unroll
      for (int r = 0; r < 16; ++r) {
        int row = rb * 64 + sub * 32 + (r & 3) + 8 * (r >> 2) + 4 * lhi;
        lT[row * 136 + col] = f2bf(acc[sub][bt][r]);
      }
    }
  __syncthreads();

#pragma unroll
  for (int i = 0; i < 8; ++i) {
    int G = i * 256 + t;
    int row = G >> 4, gg = G & 15;
    uint4 v = *reinterpret_cast<const uint4*>(&lT[row * 136 + gg * 8]);
    *reinterpret_cast<uint4*>(&hbf[(size_t)(row0 + row) * 512 + col0 + gg * 8]) = v;
  }
  {
    const int r2 = t >> 1, half = t & 1;
    float d1 = 0.f, d2 = 0.f;
#pragma unroll
    for (int i = 0; i < 8; ++i) {
      uint4 v = *reinterpret_cast<const uint4*>(&lT[r2 * 136 + half * 64 + i * 8]);
      u32 wds[4] = {v.x, v.y, v.z, v.w};
#pragma unroll
      for (int jj = 0; jj < 8; ++jj) {
        float h = bf2f((u16)(wds[jj >> 1] >> ((jj & 1) * 16)));
        d1 += h * a_l[half * 64 + i * 8 + jj];
        d2 += h * a_l[128 + half * 64 + i * 8 + jj];
      }
    }
    d1 += __shfl_xor(d1, 1);
    d2 += __shfl_xor(d2, 1);
    if (half == 0) {
      s1p[cb * 16384 + row0 + r2] = d1;
      s2p[cb * 16384 + row0 + r2] = d2;
    }
  }
}

// ---------- reduce score partials -> s1L, s2L (scaled by log2e) ----------
__global__ __launch_bounds__(256) void k_reduce(const float* __restrict__ s1p, const float* __restrict__ s2p,
                                                float* __restrict__ s1L, float* __restrict__ s2L) {
  int id = blockIdx.x * 256 + threadIdx.x;
  float d1 = s1p[id] + s1p[16384 + id] + s1p[32768 + id] + s1p[49152 + id];
  float d2 = s2p[id] + s2p[16384 + id] + s2p[32768 + id] + s2p[49152 + id];
  s1L[id] = d1 * LOG2E;
  s2L[id] = d2 * LOG2E;
}

// ---------- prep: per batch, sort s2L; E1/E2; scans -> exact denominators; kn; ipos ----------
__global__ __launch_bounds__(1024) void k_prep(const float* __restrict__ s1Lg, const float* __restrict__ s2Lg,
                                               float* __restrict__ e1s, float* __restrict__ e2s,
                                               u32* __restrict__ permM, u32* __restrict__ kng,
                                               u32* __restrict__ iposg, float* __restrict__ invd) {
  __shared__ u64 sk[1024];
  __shared__ float s2sv[1024];
  __shared__ float arrA[1024];   // incl prefix scan of E2
  __shared__ float arrB[1024];   // incl scan of reversed E1 (suffix sums)
  const int b = blockIdx.x;
  const int t = threadIdx.x;

  {
    float v = s2Lg[b * 1024 + t];
    u32 bits = __builtin_bit_cast(u32, v);
    u32 key = (bits & 0x80000000u) ? ~bits : (bits | 0x80000000u);
    sk[t] = ((u64)key << 32) | (u32)t;
  }
  for (int size = 2; size <= 1024; size <<= 1)
    for (int stride = size >> 1; stride > 0; stride >>= 1) {
      __syncthreads();
      int ixj = t ^ stride;
      if (ixj > t) {
        u64 va = sk[t], vb = sk[ixj];
        bool asc = ((t & size) == 0);
        if ((va > vb) == asc) { sk[t] = vb; sk[ixj] = va; }
      }
    }
  __syncthreads();

  const u32 idx = (u32)(sk[t] & 1023u);
  const float sv = s2Lg[b * 1024 + idx];
  s2sv[t] = sv;
  __syncthreads();

  const float E1 = exp2f(sv), E2 = exp2f(ALPHA * sv);
  e1s[b * 1024 + t] = E1;
  e2s[b * 1024 + t] = E2;
  permM[b * 1024 + t] = idx;
  iposg[b * 1024 + idx] = (u32)t;
  arrA[t] = E2;
  arrB[t] = exp2f(s2sv[1023 - t]);
  __syncthreads();

  for (int off = 1; off < 1024; off <<= 1) {
    float aA = (t >= off) ? arrA[t - off] : 0.f;
    float aB = (t >= off) ? arrB[t - off] : 0.f;
    __syncthreads();
    arrA[t] += aA;
    arrB[t] += aB;
    __syncthreads();
  }

  {
    const float s1v = s1Lg[b * 1024 + t];
    const float thr = -s1v;
    int lo = 0, hi = 1024;
    while (lo < hi) { int mid = (lo + hi) >> 1; if (s2sv[mid] <= thr) lo = mid + 1; else hi = mid; }
    const int kn = lo;
    float se1suf = (kn == 1024) ? 0.f : arrB[1023 - kn];
    float se2pre = (kn == 0) ? 0.f : arrA[kn - 1];
    float den = exp2f(s1v) * se1suf + exp2f(ALPHA * s1v) * se2pre;
    invd[b * 1024 + t] = 1.0f / den;
    kng[b * 1024 + t] = (u32)kn;
  }
}

// ---------- sweep2: per (b, 32-f chunk): stage sorted h; chunk sums; two-level
// scans -> Suf1/Pre2; per row: A/B via <=15-elem partial; fused elu output. ----------
__global__ __launch_bounds__(256, 1) void k_sweep2(const u16* __restrict__ hbf,
                                                   const float* __restrict__ e1s, const float* __restrict__ e2s,
                                                   const u32* __restrict__ permM, const u32* __restrict__ kng,
                                                   const u32* __restrict__ iposg,
                                                   const float* __restrict__ s1Lg, const float* __restrict__ invdg,
                                                   const float* __restrict__ betag, float* __restrict__ out) {
  __shared__ __attribute__((aligned(16))) u16 h_s[1024][32];   // 64 KB, sorted order
  __shared__ float e1_l[1024];
  __shared__ float e2_l[1024];
  __shared__ float C1[65][32];   // -> inclusive suffix of chunk sums (weight e1)
  __shared__ float C2[65][32];   // -> exclusive prefix of chunk sums (weight e2)
  __shared__ float segS1[8][32];
  __shared__ float segP2[8][32];
  __shared__ u32 kn_l[1024];
  __shared__ u32 ip_l[1024];
  __shared__ float s1_l[1024];
  __shared__ float inv_l[1024];

  const int t = threadIdx.x;
  const int B = blockIdx.x;
  const int b = (B & 7) * 2 + ((B >> 3) & 1);   // XCD swizzle: all fc of a batch share an XCD
  const int fc = B >> 4;                         // 0..15 : 32-f chunk

#pragma unroll
  for (int q = 0; q < 4; ++q) {
    int i = q * 256 + t;
    e1_l[i] = e1s[b * 1024 + i];
    e2_l[i] = e2s[b * 1024 + i];
    kn_l[i] = kng[b * 1024 + i];
    ip_l[i] = iposg[b * 1024 + i];
    s1_l[i] = s1Lg[b * 1024 + i];
    inv_l[i] = invdg[b * 1024 + i];
  }

  // stage h in sorted order: 16 iters x (64 rows x 4 threads of 16B)
  const int fq = t & 3;
  const int rr = t >> 2;
#pragma unroll 4
  for (int it = 0; it < 16; ++it) {
    int i = it * 64 + rr;
    u32 m = permM[b * 1024 + i];
    uint4 v = *reinterpret_cast<const uint4*>(hbf + ((size_t)b * 1024 + m) * 512 + fc * 32 + fq * 8);
    *reinterpret_cast<uint4*>(&h_s[i][fq * 8]) = v;
  }
  __syncthreads();

  // phase 1: chunk sums; thread (seg=t>>5, f=t&31) owns chunks [seg*8, seg*8+8)
  const int f = t & 31;
  const int seg = t >> 5;
  float sv1[8], sv2[8];
  float ss1 = 0.f, ss2 = 0.f;
#pragma unroll
  for (int k = 0; k < 8; ++k) {
    const int c = seg * 8 + k;
    float a1 = 0.f, a2 = 0.f;
#pragma unroll
    for (int ii = 0; ii < 16; ++ii) {
      const int i = c * 16 + ii;
      float hv = bf2f(h_s[i][f]);
      a1 = fmaf(e1_l[i], hv, a1);
      a2 = fmaf(e2_l[i], hv, a2);
    }
    sv1[k] = a1; sv2[k] = a2;
    ss1 += a1; ss2 += a2;
  }
  segS1[seg][f] = ss1;
  segP2[seg][f] = ss2;
  __syncthreads();

  if (t < 32) {   // per f: segment-level suffix (S1) and exclusive prefix (P2)
    float run = 0.f;
#pragma unroll
    for (int s7 = 7; s7 >= 0; --s7) { run += segS1[s7][t]; segS1[s7][t] = run; }
    float run2 = 0.f;
#pragma unroll
    for (int s7 = 0; s7 < 8; ++s7) { float tmp = segP2[s7][t]; segP2[s7][t] = run2; run2 += tmp; }
    C2[64][t] = run2;   // grand total prefix (kn==1024 sentinel)
    C1[64][t] = 0.f;    // empty suffix sentinel
  }
  __syncthreads();

  {
    float run = (seg < 7) ? segS1[seg + 1][f] : 0.f;   // suffix strictly after my segment
#pragma unroll
    for (int k = 7; k >= 0; --k) {
      run += sv1[k];
      C1[seg * 8 + k][f] = run;                        // = sum_{c'>=c} chunk1
    }
    float run2 = segP2[seg][f];                        // prefix strictly before my segment
#pragma unroll
    for (int k = 0; k < 8; ++k) {
      C2[seg * 8 + k][f] = run2;                       // = sum_{c'<c} chunk2
      run2 += sv2[k];
    }
  }
  __syncthreads();

  // phase 2: per row n: A = Suf1[cn] - partial1, B = Pre2[cn] + partial2; fused output
  const float beta = betag[0];
  const int nl = t >> 5;   // 0..7
#pragma unroll 2
  for (int r = 0; r < 128; ++r) {
    const int n = r * 8 + nl;
    const u32 kn = kn_l[n];
    const int cn = kn >> 4;
    const int rn = kn & 15;
    const int i0 = cn * 16;
    float p1 = 0.f, p2 = 0.f;
    for (int ii = 0; ii < rn; ++ii) {
      float hv = bf2f(h_s[i0 + ii][f]);
      p1 = fmaf(e1_l[i0 + ii], hv, p1);
      p2 = fmaf(e2_l[i0 + ii], hv, p2);
    }
    const float A = C1[cn][f] - p1;
    const float Bv = C2[cn][f] + p2;
    const float s1v = s1_l[n];
    const float num = exp2f(s1v) * A + exp2f(ALPHA * s1v) * Bv;
    const float hvn = bf2f(h_s[ip_l[n]][f]);
    const float xv = num * inv_l[n] + beta * hvn;
    out[((size_t)b * 1024 + n) * 512 + fc * 32 + f] = xv > 0.f ? xv : __expf(xv) - 1.0f;
  }
}

extern "C" void kernel_launch(void* const* d_in, const int* in_sizes, int n_in,
                              void* d_out, int out_size, void* d_ws, size_t ws_size,
                              hipStream_t stream) {
  const float* x = (const float*)d_in[0];
  const float* W = (const float*)d_in[1];
  const float* a = (const float*)d_in[2];
  const float* beta = (const float*)d_in[3];
  float* out = (float*)d_out;

  char* ws = (char*)d_ws;
  u16* hbf = (u16*)ws;                                   // [0, 16M)
  char* sm = ws + (16u << 20);
  float* e1s = (float*)(sm);                             // 64 KB each
  float* e2s = (float*)(sm + (64u << 10));
  u32* permM = (u32*)(sm + (128u << 10));
  u32* kng = (u32*)(sm + (192u << 10));
  u32* iposg = (u32*)(sm + (256u << 10));
  float* invd = (float*)(sm + (320u << 10));
  float* s1L = (float*)(sm + (384u << 10));
  float* s2L = (float*)(sm + (448u << 10));
  float* s1p = (float*)(sm + (512u << 10));              // 256 KB
  float* s2p = (float*)(sm + (768u << 10));              // 256 KB
  u16* wbt = (u16*)(sm + (1024u << 10));                 // 512 KB

  k_cast_wT<<<1024, 256, 0, stream>>>(W, wbt);
  k_gemm1<<<512, 256, 0, stream>>>(x, wbt, a, hbf, s1p, s2p);
  k_reduce<<<64, 256, 0, stream>>>(s1p, s2p, s1L, s2L);
  k_prep<<<16, 1024, 0, stream>>>(s1L, s2L, e1s, e2s, permM, kng, iposg, invd);
  k_sweep2<<<256, 256, 0, stream>>>(hbf, e1s, e2s, permM, kng, iposg, s1L, invd, beta, out);
}

// Round 14
// 91.515 us; speedup vs baseline: 2.2878x; 1.4138x over previous
//
#include <hip/hip_runtime.h>

using u16 = unsigned short;
using u32 = unsigned int;
using u64 = unsigned long long;

#define ALPHA 0.2f
#define LOG2E 1.4426950408889634f

typedef __bf16 bf16x8 __attribute__((ext_vector_type(8)));
typedef float f32x4 __attribute__((ext_vector_type(4)));
typedef float f32x16 __attribute__((ext_vector_type(16)));

__device__ __forceinline__ u16 f2bf(float f) {
  u32 u = __builtin_bit_cast(u32, f);
  u += 0x7FFFu + ((u >> 16) & 1u);   // RTNE
  return (u16)(u >> 16);
}
__device__ __forceinline__ float bf2f(u16 h) {
  u32 u = ((u32)h) << 16;
  return __builtin_bit_cast(float, u);
}
__device__ __forceinline__ void gload_lds16(const void* g, void* l) {
  __builtin_amdgcn_global_load_lds((__attribute__((address_space(1))) void*)g,
                                   (__attribute__((address_space(3))) void*)l,
                                   16, 0, 0);
}

// ---------- cast+transpose W: wbt[n][k] = bf16(W[k][n]) ----------
__global__ __launch_bounds__(256) void k_cast_wT(const float* __restrict__ W, u16* __restrict__ wbt) {
  int idx = blockIdx.x * 256 + threadIdx.x;
  int k = idx >> 9, n = idx & 511;
  wbt[n * 512 + k] = f2bf(W[idx]);
}

// ---------- gemm1: h = x@W (M=16384,K=512,N=512). 128x128 tile, 4 waves.
// Triple-buffered, counted vmcnt, XCD-swizzled. Epilogue: hbf + score partials.
__global__ __launch_bounds__(256, 2) void k_gemm1(const float* __restrict__ x, const u16* __restrict__ wbt,
                                                  const float* __restrict__ a,
                                                  u16* __restrict__ hbf,
                                                  float* __restrict__ s1p, float* __restrict__ s2p) {
  __shared__ __attribute__((aligned(16))) char lds[73728];
  __shared__ __attribute__((aligned(16))) float a_l[256];

  const int t = threadIdx.x;
  const int lane = t & 63;
  const int w = t >> 6;
  const int l31 = lane & 31, lhi = lane >> 5;
  const int rb = w >> 1, cg = w & 1;
  const int g = blockIdx.x;
  const int cb = (g >> 3) & 3;
  const int tile_m = (g & 7) | ((g >> 5) << 3);
  const int row0 = tile_m * 128;
  const int col0 = cb * 128;

  a_l[t] = (t < 128) ? a[col0 + t] : a[512 + col0 + (t - 128)];

  f32x16 acc[2][2];
#pragma unroll
  for (int i = 0; i < 2; ++i)
#pragma unroll
    for (int j = 0; j < 2; ++j)
#pragma unroll
      for (int r = 0; r < 16; ++r) acc[i][j][r] = 0.f;

#define STAGE_G1(kt, Ab, Bb)                                                              \
  {                                                                                       \
    const int k0_ = (kt) * 32;                                                            \
    _Pragma("unroll")                                                                     \
    for (int i = 0; i < 4; ++i) {                                                         \
      int G = i * 256 + t;                                                                \
      int row = G >> 3, ks = G & 7;                                                       \
      gload_lds16(x + (size_t)(row0 + row) * 512 + k0_ + ((ks ^ (row & 7)) * 4),          \
                  (Ab) + (size_t)(i * 256 + w * 64) * 16);                                \
    }                                                                                     \
    _Pragma("unroll")                                                                     \
    for (int i = 0; i < 2; ++i) {                                                         \
      int G = i * 256 + t;                                                                \
      int col = G >> 2, ks = G & 3;                                                       \
      gload_lds16(wbt + (size_t)(col0 + col) * 512 + k0_ + ((ks ^ ((col >> 1) & 3)) * 8), \
                  (Bb) + (size_t)(i * 256 + w * 64) * 16);                                \
    }                                                                                     \
  }

#define COMPUTE_G1(Ab, Bb)                                                                         \
  {                                                                                                \
    _Pragma("unroll")                                                                              \
    for (int ks = 0; ks < 2; ++ks) {                                                               \
      bf16x8 af[2];                                                                                \
      _Pragma("unroll")                                                                            \
      for (int sub = 0; sub < 2; ++sub) {                                                          \
        const int arow = rb * 64 + sub * 32 + l31;                                                 \
        const int kg = ks * 4 + lhi * 2;                                                           \
        f32x4 fa0 = *reinterpret_cast<const f32x4*>((Ab) + (size_t)(arow * 8 + (kg ^ (arow & 7))) * 16); \
        f32x4 fa1 = *reinterpret_cast<const f32x4*>((Ab) + (size_t)(arow * 8 + ((kg + 1) ^ (arow & 7))) * 16); \
        _Pragma("unroll")                                                                          \
        for (int jj = 0; jj < 4; ++jj) {                                                           \
          af[sub][jj] = (__bf16)fa0[jj];                                                           \
          af[sub][jj + 4] = (__bf16)fa1[jj];                                                       \
        }                                                                                          \
      }                                                                                            \
      bf16x8 bfr[2];                                                                               \
      _Pragma("unroll")                                                                            \
      for (int bt = 0; bt < 2; ++bt) {                                                             \
        const int bcol = cg * 64 + bt * 32 + l31;                                                  \
        const int kslot = (ks * 2 + lhi) ^ ((bcol >> 1) & 3);                                      \
        bfr[bt] = *reinterpret_cast<const bf16x8*>((Bb) + (size_t)(bcol * 4 + kslot) * 16);        \
      }                                                                                            \
      _Pragma("unroll")                                                                            \
      for (int sub = 0; sub < 2; ++sub)                                                            \
        _Pragma("unroll")                                                                          \
        for (int bt = 0; bt < 2; ++bt)                                                             \
          acc[sub][bt] = __builtin_amdgcn_mfma_f32_32x32x16_bf16(af[sub], bfr[bt], acc[sub][bt], 0, 0, 0); \
    }                                                                                              \
  }

  char* Ac = lds;             char* Bc = lds + 49152;
  char* An = lds + 16384;     char* Bn = lds + 57344;
  char* As = lds + 32768;     char* Bs = lds + 65536;

  STAGE_G1(0, Ac, Bc);
  STAGE_G1(1, An, Bn);
  __builtin_amdgcn_sched_barrier(0);
  asm volatile("s_waitcnt vmcnt(6) lgkmcnt(0)" ::: "memory");
  __builtin_amdgcn_s_barrier();
  __builtin_amdgcn_sched_barrier(0);

#pragma unroll 1
  for (int kt = 0; kt < 14; ++kt) {
    STAGE_G1(kt + 2, As, Bs);
    COMPUTE_G1(Ac, Bc);
    __builtin_amdgcn_sched_barrier(0);
    asm volatile("s_waitcnt vmcnt(6)" ::: "memory");
    __builtin_amdgcn_s_barrier();
    __builtin_amdgcn_sched_barrier(0);
    char* ta = Ac; Ac = An; An = As; As = ta;
    char* tb = Bc; Bc = Bn; Bn = Bs; Bs = tb;
  }
  COMPUTE_G1(Ac, Bc);
  __builtin_amdgcn_sched_barrier(0);
  asm volatile("s_waitcnt vmcnt(0)" ::: "memory");
  __builtin_amdgcn_s_barrier();
  __builtin_amdgcn_sched_barrier(0);
  COMPUTE_G1(An, Bn);
#undef STAGE_G1
#undef COMPUTE_G1

  __syncthreads();

  u16* lT = (u16*)lds;
#pragma unroll
  for (int sub = 0; sub < 2; ++sub)
#pragma unroll
    for (int bt = 0; bt < 2; ++bt) {
      const int col = cg * 64 + bt * 32 + l31;
#pragma unroll
      for (int r = 0; r < 16; ++r) {
        int row = rb * 64 + sub * 32 + (r & 3) + 8 * (r >> 2) + 4 * lhi;
        lT[row * 136 + col] = f2bf(acc[sub][bt][r]);
      }
    }
  __syncthreads();

#pragma unroll
  for (int i = 0; i < 8; ++i) {
    int G = i * 256 + t;
    int row = G >> 4, gg = G & 15;
    uint4 v = *reinterpret_cast<const uint4*>(&lT[row * 136 + gg * 8]);
    *reinterpret_cast<uint4*>(&hbf[(size_t)(row0 + row) * 512 + col0 + gg * 8]) = v;
  }
  {
    const int r2 = t >> 1, half = t & 1;
    float d1 = 0.f, d2 = 0.f;
#pragma unroll
    for (int i = 0; i < 8; ++i) {
      uint4 v = *reinterpret_cast<const uint4*>(&lT[r2 * 136 + half * 64 + i * 8]);
      u32 wds[4] = {v.x, v.y, v.z, v.w};
#pragma unroll
      for (int jj = 0; jj < 8; ++jj) {
        float h = bf2f((u16)(wds[jj >> 1] >> ((jj & 1) * 16)));
        d1 += h * a_l[half * 64 + i * 8 + jj];
        d2 += h * a_l[128 + half * 64 + i * 8 + jj];
      }
    }
    d1 += __shfl_xor(d1, 1);
    d2 += __shfl_xor(d2, 1);
    if (half == 0) {
      s1p[cb * 16384 + row0 + r2] = d1;
      s2p[cb * 16384 + row0 + r2] = d2;
    }
  }
}

// ---------- prep (k_reduce fused): per batch, reduce partials; sort s2L; E1/E2;
// scans -> exact denominators; kn; ipos. ----------
__global__ __launch_bounds__(1024) void k_prep(const float* __restrict__ s1p, const float* __restrict__ s2p,
                                               float* __restrict__ s1Lg,
                                               float* __restrict__ e1s, float* __restrict__ e2s,
                                               u32* __restrict__ permM, u32* __restrict__ kng,
                                               u32* __restrict__ iposg, float* __restrict__ invd) {
  __shared__ u64 sk[1024];
  __shared__ float s2all[1024];
  __shared__ float s2sv[1024];
  __shared__ float arrA[1024];
  __shared__ float arrB[1024];
  const int b = blockIdx.x;
  const int t = threadIdx.x;
  const int id = b * 1024 + t;

  // fused reduce
  const float s1v = (s1p[id] + s1p[16384 + id] + s1p[32768 + id] + s1p[49152 + id]) * LOG2E;
  const float s2v = (s2p[id] + s2p[16384 + id] + s2p[32768 + id] + s2p[49152 + id]) * LOG2E;
  s1Lg[id] = s1v;
  s2all[t] = s2v;

  {
    u32 bits = __builtin_bit_cast(u32, s2v);
    u32 key = (bits & 0x80000000u) ? ~bits : (bits | 0x80000000u);
    sk[t] = ((u64)key << 32) | (u32)t;
  }
  for (int size = 2; size <= 1024; size <<= 1)
    for (int stride = size >> 1; stride > 0; stride >>= 1) {
      __syncthreads();
      int ixj = t ^ stride;
      if (ixj > t) {
        u64 va = sk[t], vb = sk[ixj];
        bool asc = ((t & size) == 0);
        if ((va > vb) == asc) { sk[t] = vb; sk[ixj] = va; }
      }
    }
  __syncthreads();

  const u32 idx = (u32)(sk[t] & 1023u);
  const float sv = s2all[idx];
  s2sv[t] = sv;
  __syncthreads();

  const float E1 = exp2f(sv), E2 = exp2f(ALPHA * sv);
  e1s[b * 1024 + t] = E1;
  e2s[b * 1024 + t] = E2;
  permM[b * 1024 + t] = idx;
  iposg[b * 1024 + idx] = (u32)t;
  arrA[t] = E2;
  arrB[t] = exp2f(s2sv[1023 - t]);
  __syncthreads();

  for (int off = 1; off < 1024; off <<= 1) {
    float aA = (t >= off) ? arrA[t - off] : 0.f;
    float aB = (t >= off) ? arrB[t - off] : 0.f;
    __syncthreads();
    arrA[t] += aA;
    arrB[t] += aB;
    __syncthreads();
  }

  {
    const float thr = -s1v;
    int lo = 0, hi = 1024;
    while (lo < hi) { int mid = (lo + hi) >> 1; if (s2sv[mid] <= thr) lo = mid + 1; else hi = mid; }
    const int kn = lo;
    float se1suf = (kn == 1024) ? 0.f : arrB[1023 - kn];
    float se2pre = (kn == 0) ? 0.f : arrA[kn - 1];
    float den = exp2f(s1v) * se1suf + exp2f(ALPHA * s1v) * se2pre;
    invd[id] = 1.0f / den;
    kng[id] = (u32)kn;
  }
}

// ---------- sweep2: per (b, 32-f chunk): stage sorted h; chunk-4 sums; two-level
// scans -> C1 (suffix, f32) / C2 (excl prefix, f32); per row: <=3-elem predicated
// partial; fused elu output. ----------
__global__ __launch_bounds__(256, 1) void k_sweep2(const u16* __restrict__ hbf,
                                                   const float* __restrict__ e1s, const float* __restrict__ e2s,
                                                   const u32* __restrict__ permM, const u32* __restrict__ kng,
                                                   const u32* __restrict__ iposg,
                                                   const float* __restrict__ s1Lg, const float* __restrict__ invdg,
                                                   const float* __restrict__ betag, float* __restrict__ out) {
  __shared__ __attribute__((aligned(16))) u16 h_s[1024][32];   // 64 KB, sorted order
  __shared__ float C1[257][32];                                 // suffix sums (incl), f32
  __shared__ float C2[257][32];                                 // exclusive prefix sums
  __shared__ float e1_l[1024];
  __shared__ float e2_l[1024];
  __shared__ float s1_l[1024];
  __shared__ float inv_l[1024];
  __shared__ u16 kn_l[1024];
  __shared__ u16 ip_l[1024];
  __shared__ float segS1[8][32];
  __shared__ float segP2[8][32];

  const int t = threadIdx.x;
  const int B = blockIdx.x;
  const int b = (B & 7) * 2 + ((B >> 3) & 1);   // XCD swizzle: all fc of a batch share an XCD
  const int fc = B >> 4;                         // 0..15 : 32-f chunk

#pragma unroll
  for (int q = 0; q < 4; ++q) {
    int i = q * 256 + t;
    e1_l[i] = e1s[b * 1024 + i];
    e2_l[i] = e2s[b * 1024 + i];
    s1_l[i] = s1Lg[b * 1024 + i];
    inv_l[i] = invdg[b * 1024 + i];
    kn_l[i] = (u16)kng[b * 1024 + i];
    ip_l[i] = (u16)iposg[b * 1024 + i];
  }

  // stage h in sorted order
  const int fq = t & 3;
  const int rr = t >> 2;
#pragma unroll 4
  for (int it = 0; it < 16; ++it) {
    int i = it * 64 + rr;
    u32 m = permM[b * 1024 + i];
    uint4 v = *reinterpret_cast<const uint4*>(hbf + ((size_t)b * 1024 + m) * 512 + fc * 32 + fq * 8);
    *reinterpret_cast<uint4*>(&h_s[i][fq * 8]) = v;
  }
  __syncthreads();

  // phase 1: 256 chunks of 4; thread (seg=t>>5, f=t&31) owns chunks [seg*32, seg*32+32)
  const int f = t & 31;
  const int seg = t >> 5;
  float ch1[32], ch2[32];
  float ss1 = 0.f, ss2 = 0.f;
#pragma unroll
  for (int c = 0; c < 32; ++c) {
    const int i0 = seg * 128 + c * 4;
    float a1 = 0.f, a2 = 0.f;
#pragma unroll
    for (int ii = 0; ii < 4; ++ii) {
      float hv = bf2f(h_s[i0 + ii][f]);
      a1 = fmaf(e1_l[i0 + ii], hv, a1);
      a2 = fmaf(e2_l[i0 + ii], hv, a2);
    }
    ch1[c] = a1; ch2[c] = a2;
    ss1 += a1; ss2 += a2;
  }
  segS1[seg][f] = ss1;
  segP2[seg][f] = ss2;
  __syncthreads();

  float sufAfter = 0.f, preBefore = 0.f, totP2 = 0.f;
#pragma unroll
  for (int s7 = 0; s7 < 8; ++s7) {
    float v1 = segS1[s7][f];
    float v2 = segP2[s7][f];
    if (s7 > seg) sufAfter += v1;
    if (s7 < seg) preBefore += v2;
    totP2 += v2;
  }
  {
    float run1 = sufAfter;
#pragma unroll
    for (int c = 31; c >= 0; --c) { run1 += ch1[c]; C1[seg * 32 + c][f] = run1; }
    float run2 = preBefore;
#pragma unroll
    for (int c = 0; c < 32; ++c) { C2[seg * 32 + c][f] = run2; run2 += ch2[c]; }
  }
  if (seg == 0) { C1[256][f] = 0.f; C2[256][f] = totP2; }
  __syncthreads();

  // phase 2: per row n: A = C1[cn] - partial1, B = C2[cn] + partial2 (<=3 predicated)
  const float beta = betag[0];
  const int nl = t >> 5;
#pragma unroll 4
  for (int r = 0; r < 128; ++r) {
    const int n = r * 8 + nl;
    const int kn = kn_l[n];
    const int cn = kn >> 2;
    const int rn = kn & 3;
    const int i0 = cn * 4;
    float p1 = 0.f, p2 = 0.f;
#pragma unroll
    for (int ii = 0; ii < 3; ++ii) {
      int idx = i0 + ii;
      idx = idx > 1023 ? 1023 : idx;
      float hv = bf2f(h_s[idx][f]);
      float w1 = (ii < rn) ? e1_l[idx] : 0.f;
      float w2 = (ii < rn) ? e2_l[idx] : 0.f;
      p1 = fmaf(w1, hv, p1);
      p2 = fmaf(w2, hv, p2);
    }
    const float A = C1[cn][f] - p1;
    const float Bv = C2[cn][f] + p2;
    const float s1v = s1_l[n];
    const float num = exp2f(s1v) * A + exp2f(ALPHA * s1v) * Bv;
    const float hvn = bf2f(h_s[ip_l[n]][f]);
    const float xv = num * inv_l[n] + beta * hvn;
    out[((size_t)b * 1024 + n) * 512 + fc * 32 + f] = xv > 0.f ? xv : __expf(xv) - 1.0f;
  }
}

extern "C" void kernel_launch(void* const* d_in, const int* in_sizes, int n_in,
                              void* d_out, int out_size, void* d_ws, size_t ws_size,
                              hipStream_t stream) {
  const float* x = (const float*)d_in[0];
  const float* W = (const float*)d_in[1];
  const float* a = (const float*)d_in[2];
  const float* beta = (const float*)d_in[3];
  float* out = (float*)d_out;

  char* ws = (char*)d_ws;
  u16* hbf = (u16*)ws;                                   // [0, 16M)
  char* sm = ws + (16u << 20);
  float* e1s = (float*)(sm);                             // 64 KB each
  float* e2s = (float*)(sm + (64u << 10));
  u32* permM = (u32*)(sm + (128u << 10));
  u32* kng = (u32*)(sm + (192u << 10));
  u32* iposg = (u32*)(sm + (256u << 10));
  float* invd = (float*)(sm + (320u << 10));
  float* s1L = (float*)(sm + (384u << 10));
  float* s1p = (float*)(sm + (512u << 10));              // 256 KB
  float* s2p = (float*)(sm + (768u << 10));              // 256 KB
  u16* wbt = (u16*)(sm + (1024u << 10));                 // 512 KB

  k_cast_wT<<<1024, 256, 0, stream>>>(W, wbt);
  k_gemm1<<<512, 256, 0, stream>>>(x, wbt, a, hbf, s1p, s2p);
  k_prep<<<16, 1024, 0, stream>>>(s1p, s2p, s1L, e1s, e2s, permM, kng, iposg, invd);
  k_sweep2<<<256, 256, 0, stream>>>(hbf, e1s, e2s, permM, kng, iposg, s1L, invd, beta, out);
}

// Round 15
// 74.381 us; speedup vs baseline: 2.8149x; 1.2304x over previous
//
#include <hip/hip_runtime.h>

using u16 = unsigned short;
using u32 = unsigned int;
using u64 = unsigned long long;

#define ALPHA 0.2f
#define LOG2E 1.4426950408889634f

typedef __bf16 bf16x8 __attribute__((ext_vector_type(8)));
typedef float f32x4 __attribute__((ext_vector_type(4)));
typedef float f32x16 __attribute__((ext_vector_type(16)));

__device__ __forceinline__ u16 f2bf(float f) {
  u32 u = __builtin_bit_cast(u32, f);
  u += 0x7FFFu + ((u >> 16) & 1u);   // RTNE
  return (u16)(u >> 16);
}
__device__ __forceinline__ float bf2f(u16 h) {
  u32 u = ((u32)h) << 16;
  return __builtin_bit_cast(float, u);
}
__device__ __forceinline__ void gload_lds16(const void* g, void* l) {
  __builtin_amdgcn_global_load_lds((__attribute__((address_space(1))) void*)g,
                                   (__attribute__((address_space(3))) void*)l,
                                   16, 0, 0);
}

// ---------- cast+transpose W: wbt[n][k] = bf16(W[k][n]) ----------
__global__ __launch_bounds__(256) void k_cast_wT(const float* __restrict__ W, u16* __restrict__ wbt) {
  int idx = blockIdx.x * 256 + threadIdx.x;
  int k = idx >> 9, n = idx & 511;
  wbt[n * 512 + k] = f2bf(W[idx]);
}

// ---------- gemm1: h = x@W (M=16384,K=512,N=512). 128x128 tile, 4 waves.
// Triple-buffered, counted vmcnt, XCD-swizzled. Epilogue: hbf + score partials.
__global__ __launch_bounds__(256, 2) void k_gemm1(const float* __restrict__ x, const u16* __restrict__ wbt,
                                                  const float* __restrict__ a,
                                                  u16* __restrict__ hbf,
                                                  float* __restrict__ s1p, float* __restrict__ s2p) {
  __shared__ __attribute__((aligned(16))) char lds[73728];
  __shared__ __attribute__((aligned(16))) float a_l[256];

  const int t = threadIdx.x;
  const int lane = t & 63;
  const int w = t >> 6;
  const int l31 = lane & 31, lhi = lane >> 5;
  const int rb = w >> 1, cg = w & 1;
  const int g = blockIdx.x;
  const int cb = (g >> 3) & 3;
  const int tile_m = (g & 7) | ((g >> 5) << 3);
  const int row0 = tile_m * 128;
  const int col0 = cb * 128;

  a_l[t] = (t < 128) ? a[col0 + t] : a[512 + col0 + (t - 128)];

  f32x16 acc[2][2];
#pragma unroll
  for (int i = 0; i < 2; ++i)
#pragma unroll
    for (int j = 0; j < 2; ++j)
#pragma unroll
      for (int r = 0; r < 16; ++r) acc[i][j][r] = 0.f;

#define STAGE_G1(kt, Ab, Bb)                                                              \
  {                                                                                       \
    const int k0_ = (kt) * 32;                                                            \
    _Pragma("unroll")                                                                     \
    for (int i = 0; i < 4; ++i) {                                                         \
      int G = i * 256 + t;                                                                \
      int row = G >> 3, ks = G & 7;                                                       \
      gload_lds16(x + (size_t)(row0 + row) * 512 + k0_ + ((ks ^ (row & 7)) * 4),          \
                  (Ab) + (size_t)(i * 256 + w * 64) * 16);                                \
    }                                                                                     \
    _Pragma("unroll")                                                                     \
    for (int i = 0; i < 2; ++i) {                                                         \
      int G = i * 256 + t;                                                                \
      int col = G >> 2, ks = G & 3;                                                       \
      gload_lds16(wbt + (size_t)(col0 + col) * 512 + k0_ + ((ks ^ ((col >> 1) & 3)) * 8), \
                  (Bb) + (size_t)(i * 256 + w * 64) * 16);                                \
    }                                                                                     \
  }

#define COMPUTE_G1(Ab, Bb)                                                                         \
  {                                                                                                \
    _Pragma("unroll")                                                                              \
    for (int ks = 0; ks < 2; ++ks) {                                                               \
      bf16x8 af[2];                                                                                \
      _Pragma("unroll")                                                                            \
      for (int sub = 0; sub < 2; ++sub) {                                                          \
        const int arow = rb * 64 + sub * 32 + l31;                                                 \
        const int kg = ks * 4 + lhi * 2;                                                           \
        f32x4 fa0 = *reinterpret_cast<const f32x4*>((Ab) + (size_t)(arow * 8 + (kg ^ (arow & 7))) * 16); \
        f32x4 fa1 = *reinterpret_cast<const f32x4*>((Ab) + (size_t)(arow * 8 + ((kg + 1) ^ (arow & 7))) * 16); \
        _Pragma("unroll")                                                                          \
        for (int jj = 0; jj < 4; ++jj) {                                                           \
          af[sub][jj] = (__bf16)fa0[jj];                                                           \
          af[sub][jj + 4] = (__bf16)fa1[jj];                                                       \
        }                                                                                          \
      }                                                                                            \
      bf16x8 bfr[2];                                                                               \
      _Pragma("unroll")                                                                            \
      for (int bt = 0; bt < 2; ++bt) {                                                             \
        const int bcol = cg * 64 + bt * 32 + l31;                                                  \
        const int kslot = (ks * 2 + lhi) ^ ((bcol >> 1) & 3);                                      \
        bfr[bt] = *reinterpret_cast<const bf16x8*>((Bb) + (size_t)(bcol * 4 + kslot) * 16);        \
      }                                                                                            \
      _Pragma("unroll")                                                                            \
      for (int sub = 0; sub < 2; ++sub)                                                            \
        _Pragma("unroll")                                                                          \
        for (int bt = 0; bt < 2; ++bt)                                                             \
          acc[sub][bt] = __builtin_amdgcn_mfma_f32_32x32x16_bf16(af[sub], bfr[bt], acc[sub][bt], 0, 0, 0); \
    }                                                                                              \
  }

  char* Ac = lds;             char* Bc = lds + 49152;
  char* An = lds + 16384;     char* Bn = lds + 57344;
  char* As = lds + 32768;     char* Bs = lds + 65536;

  STAGE_G1(0, Ac, Bc);
  STAGE_G1(1, An, Bn);
  __builtin_amdgcn_sched_barrier(0);
  asm volatile("s_waitcnt vmcnt(6) lgkmcnt(0)" ::: "memory");
  __builtin_amdgcn_s_barrier();
  __builtin_amdgcn_sched_barrier(0);

#pragma unroll 1
  for (int kt = 0; kt < 14; ++kt) {
    STAGE_G1(kt + 2, As, Bs);
    COMPUTE_G1(Ac, Bc);
    __builtin_amdgcn_sched_barrier(0);
    asm volatile("s_waitcnt vmcnt(6)" ::: "memory");
    __builtin_amdgcn_s_barrier();
    __builtin_amdgcn_sched_barrier(0);
    char* ta = Ac; Ac = An; An = As; As = ta;
    char* tb = Bc; Bc = Bn; Bn = Bs; Bs = tb;
  }
  COMPUTE_G1(Ac, Bc);
  __builtin_amdgcn_sched_barrier(0);
  asm volatile("s_waitcnt vmcnt(0)" ::: "memory");
  __builtin_amdgcn_s_barrier();
  __builtin_amdgcn_sched_barrier(0);
  COMPUTE_G1(An, Bn);
#undef STAGE_G1
#undef COMPUTE_G1

  __syncthreads();

  u16* lT = (u16*)lds;
#pragma unroll
  for (int sub = 0; sub < 2; ++sub)
#pragma unroll
    for (int bt = 0; bt < 2; ++bt) {
      const int col = cg * 64 + bt * 32 + l31;
#pragma unroll
      for (int r = 0; r < 16; ++r) {
        int row = rb * 64 + sub * 32 + (r & 3) + 8 * (r >> 2) + 4 * lhi;
        lT[row * 136 + col] = f2bf(acc[sub][bt][r]);
      }
    }
  __syncthreads();

#pragma unroll
  for (int i = 0; i < 8; ++i) {
    int G = i * 256 + t;
    int row = G >> 4, gg = G & 15;
    uint4 v = *reinterpret_cast<const uint4*>(&lT[row * 136 + gg * 8]);
    *reinterpret_cast<uint4*>(&hbf[(size_t)(row0 + row) * 512 + col0 + gg * 8]) = v;
  }
  {
    const int r2 = t >> 1, half = t & 1;
    float d1 = 0.f, d2 = 0.f;
#pragma unroll
    for (int i = 0; i < 8; ++i) {
      uint4 v = *reinterpret_cast<const uint4*>(&lT[r2 * 136 + half * 64 + i * 8]);
      u32 wds[4] = {v.x, v.y, v.z, v.w};
#pragma unroll
      for (int jj = 0; jj < 8; ++jj) {
        float h = bf2f((u16)(wds[jj >> 1] >> ((jj & 1) * 16)));
        d1 += h * a_l[half * 64 + i * 8 + jj];
        d2 += h * a_l[128 + half * 64 + i * 8 + jj];
      }
    }
    d1 += __shfl_xor(d1, 1);
    d2 += __shfl_xor(d2, 1);
    if (half == 0) {
      s1p[cb * 16384 + row0 + r2] = d1;
      s2p[cb * 16384 + row0 + r2] = d2;
    }
  }
}

// ---------- prep: reduce partials; u32-key bitonic sort of s2L; E1/E2; scans ->
// exact denominators folded into c1i/c2i; kn. ----------
__global__ __launch_bounds__(1024) void k_prep(const float* __restrict__ s1p, const float* __restrict__ s2p,
                                               float* __restrict__ e1s, float* __restrict__ e2s,
                                               u32* __restrict__ permM, u32* __restrict__ kng,
                                               float* __restrict__ c1ig, float* __restrict__ c2ig) {
  __shared__ u32 sk[1024];
  __shared__ float s2all[1024];
  __shared__ float s2sv[1024];
  __shared__ float arrA[1024];
  __shared__ float arrB[1024];
  const int b = blockIdx.x;
  const int t = threadIdx.x;
  const int id = b * 1024 + t;

  const float s1v = (s1p[id] + s1p[16384 + id] + s1p[32768 + id] + s1p[49152 + id]) * LOG2E;
  const float s2v = (s2p[id] + s2p[16384 + id] + s2p[32768 + id] + s2p[49152 + id]) * LOG2E;
  s2all[t] = s2v;

  {
    u32 bits = __builtin_bit_cast(u32, s2v);
    u32 key = (bits & 0x80000000u) ? ~bits : (bits | 0x80000000u);
    sk[t] = (key & 0xFFFFFC00u) | (u32)t;   // truncated key | idx (ties -> negligible e~0 branch flips)
  }
  for (int size = 2; size <= 1024; size <<= 1)
    for (int stride = size >> 1; stride > 0; stride >>= 1) {
      __syncthreads();
      int ixj = t ^ stride;
      if (ixj > t) {
        u32 va = sk[t], vb = sk[ixj];
        bool asc = ((t & size) == 0);
        if ((va > vb) == asc) { sk[t] = vb; sk[ixj] = va; }
      }
    }
  __syncthreads();

  const u32 idx = sk[t] & 1023u;
  const float sv = s2all[idx];
  s2sv[t] = sv;
  __syncthreads();

  const float E1 = exp2f(sv), E2 = exp2f(ALPHA * sv);
  e1s[b * 1024 + t] = E1;
  e2s[b * 1024 + t] = E2;
  permM[b * 1024 + t] = idx;
  arrA[t] = E2;
  arrB[t] = exp2f(s2sv[1023 - t]);
  __syncthreads();

  for (int off = 1; off < 1024; off <<= 1) {
    float aA = (t >= off) ? arrA[t - off] : 0.f;
    float aB = (t >= off) ? arrB[t - off] : 0.f;
    __syncthreads();
    arrA[t] += aA;
    arrB[t] += aB;
    __syncthreads();
  }

  {
    const float thr = -s1v;
    int lo = 0, hi = 1024;
    while (lo < hi) { int mid = (lo + hi) >> 1; if (s2sv[mid] <= thr) lo = mid + 1; else hi = mid; }
    const int kn = lo;
    float se1suf = (kn == 1024) ? 0.f : arrB[1023 - kn];
    float se2pre = (kn == 0) ? 0.f : arrA[kn - 1];
    const float c1 = exp2f(s1v), c2 = exp2f(ALPHA * s1v);
    const float inv = 1.0f / (c1 * se1suf + c2 * se2pre);
    c1ig[id] = c1 * inv;
    c2ig[id] = c2 * inv;
    kng[id] = (u32)kn;
  }
}

// ---------- sweep2: per (b, 16-f chunk): h read straight from L2 (no staging);
// chunk-4 sums -> packed bf16 C1/C2 scan table; per row <=3-elem predicated
// partial; fused elu output. LDS ~39KB -> 2 blocks/CU. ----------
__global__ __launch_bounds__(256, 2) void k_sweep2(const u16* __restrict__ hbf,
                                                   const float* __restrict__ e1s, const float* __restrict__ e2s,
                                                   const u32* __restrict__ permM, const u32* __restrict__ kng,
                                                   const float* __restrict__ c1ig, const float* __restrict__ c2ig,
                                                   const float* __restrict__ betag, float* __restrict__ out) {
  __shared__ u32 Cp[257][16];      // lo bf16 = C1 (incl suffix), hi bf16 = C2 (excl prefix)
  __shared__ float e1_l[1024];
  __shared__ float e2_l[1024];
  __shared__ float c1i_l[1024];
  __shared__ float c2i_l[1024];
  __shared__ u16 kn_l[1024];
  __shared__ u16 perm_l[1024];
  __shared__ float segS1[16][16];
  __shared__ float segP2[16][16];

  const int t = threadIdx.x;
  const int B = blockIdx.x;
  const int b = (B & 7) * 2 + ((B >> 3) & 1);   // XCD swizzle: batch's 32 blocks share an XCD
  const int fc = B >> 4;                         // 0..31 : 16-f chunk

  const u16* hB = hbf + (size_t)b * 1024 * 512 + fc * 16;

#pragma unroll
  for (int q = 0; q < 4; ++q) {
    int i = q * 256 + t;
    e1_l[i] = e1s[b * 1024 + i];
    e2_l[i] = e2s[b * 1024 + i];
    c1i_l[i] = c1ig[b * 1024 + i];
    c2i_l[i] = c2ig[b * 1024 + i];
    kn_l[i] = (u16)kng[b * 1024 + i];
    perm_l[i] = (u16)permM[b * 1024 + i];
  }
  __syncthreads();

  // phase 1: 256 chunks of 4 sorted elems; thread (seg=t>>4, f=t&15) owns 16 chunks
  const int f = t & 15;
  const int seg = t >> 4;
  float ch1[16], ch2[16];
  float ss1 = 0.f, ss2 = 0.f;
#pragma unroll
  for (int c = 0; c < 16; ++c) {
    const int i0 = seg * 64 + c * 4;
    float a1 = 0.f, a2 = 0.f;
#pragma unroll
    for (int ii = 0; ii < 4; ++ii) {
      const int i = i0 + ii;
      float hv = bf2f(hB[(size_t)perm_l[i] * 512 + f]);
      a1 = fmaf(e1_l[i], hv, a1);
      a2 = fmaf(e2_l[i], hv, a2);
    }
    ch1[c] = a1; ch2[c] = a2;
    ss1 += a1; ss2 += a2;
  }
  segS1[seg][f] = ss1;
  segP2[seg][f] = ss2;
  __syncthreads();

  float sufAfter = 0.f, preBefore = 0.f, totP2 = 0.f;
#pragma unroll
  for (int s7 = 0; s7 < 16; ++s7) {
    float v1 = segS1[s7][f];
    float v2 = segP2[s7][f];
    if (s7 > seg) sufAfter += v1;
    if (s7 < seg) preBefore += v2;
    totP2 += v2;
  }
  {
    float run1 = sufAfter;
    float c1v[16];
#pragma unroll
    for (int c = 15; c >= 0; --c) { run1 += ch1[c]; c1v[c] = run1; }
    float run2 = preBefore;
#pragma unroll
    for (int c = 0; c < 16; ++c) {
      Cp[seg * 16 + c][f] = (u32)f2bf(c1v[c]) | ((u32)f2bf(run2) << 16);
      run2 += ch2[c];
    }
  }
  if (seg == 0) Cp[256][f] = (u32)f2bf(0.f) | ((u32)f2bf(totP2) << 16);
  __syncthreads();

  // phase 2: per row n: A = C1[cn]-partial1, B = C2[cn]+partial2 (<=3 predicated);
  // fused elu output. 16 rows in flight, 64 iters.
  const float beta = betag[0];
  const int nl = t >> 4;
#pragma unroll 4
  for (int r = 0; r < 64; ++r) {
    const int n = r * 16 + nl;
    const int kn = kn_l[n];
    const int cn = kn >> 2;
    const int rn = kn & 3;
    const int i0 = cn * 4;
    float p1 = 0.f, p2 = 0.f;
#pragma unroll
    for (int ii = 0; ii < 3; ++ii) {
      int idx = i0 + ii;
      idx = idx > 1023 ? 1023 : idx;
      float hv = bf2f(hB[(size_t)perm_l[idx] * 512 + f]);
      float w1 = (ii < rn) ? e1_l[idx] : 0.f;
      float w2 = (ii < rn) ? e2_l[idx] : 0.f;
      p1 = fmaf(w1, hv, p1);
      p2 = fmaf(w2, hv, p2);
    }
    const u32 cp = Cp[cn][f];
    const float A = bf2f((u16)(cp & 0xFFFFu)) - p1;
    const float Bv = bf2f((u16)(cp >> 16)) + p2;
    const float hvn = bf2f(hB[(size_t)n * 512 + f]);
    const float xv = c1i_l[n] * A + c2i_l[n] * Bv + beta * hvn;
    out[((size_t)b * 1024 + n) * 512 + fc * 16 + f] = xv > 0.f ? xv : __expf(xv) - 1.0f;
  }
}

extern "C" void kernel_launch(void* const* d_in, const int* in_sizes, int n_in,
                              void* d_out, int out_size, void* d_ws, size_t ws_size,
                              hipStream_t stream) {
  const float* x = (const float*)d_in[0];
  const float* W = (const float*)d_in[1];
  const float* a = (const float*)d_in[2];
  const float* beta = (const float*)d_in[3];
  float* out = (float*)d_out;

  char* ws = (char*)d_ws;
  u16* hbf = (u16*)ws;                                   // [0, 16M)
  char* sm = ws + (16u << 20);
  float* e1s = (float*)(sm);                             // 64 KB each
  float* e2s = (float*)(sm + (64u << 10));
  u32* permM = (u32*)(sm + (128u << 10));
  u32* kng = (u32*)(sm + (192u << 10));
  float* c1i = (float*)(sm + (256u << 10));
  float* c2i = (float*)(sm + (320u << 10));
  float* s1p = (float*)(sm + (512u << 10));              // 256 KB
  float* s2p = (float*)(sm + (768u << 10));              // 256 KB
  u16* wbt = (u16*)(sm + (1024u << 10));                 // 512 KB

  k_cast_wT<<<1024, 256, 0, stream>>>(W, wbt);
  k_gemm1<<<512, 256, 0, stream>>>(x, wbt, a, hbf, s1p, s2p);
  k_prep<<<16, 1024, 0, stream>>>(s1p, s2p, e1s, e2s, permM, kng, c1i, c2i);
  k_sweep2<<<512, 256, 0, stream>>>(hbf, e1s, e2s, permM, kng, c1i, c2i, beta, out);
}

// Round 16
// 66.637 us; speedup vs baseline: 3.1420x; 1.1162x over previous
//
#include <hip/hip_runtime.h>

using u16 = unsigned short;
using u32 = unsigned int;
using u64 = unsigned long long;

#define ALPHA 0.2f
#define LOG2E 1.4426950408889634f

typedef __bf16 bf16x8 __attribute__((ext_vector_type(8)));
typedef float f32x4 __attribute__((ext_vector_type(4)));
typedef float f32x16 __attribute__((ext_vector_type(16)));

__device__ __forceinline__ u16 f2bf(float f) {
  u32 u = __builtin_bit_cast(u32, f);
  u += 0x7FFFu + ((u >> 16) & 1u);   // RTNE
  return (u16)(u >> 16);
}
__device__ __forceinline__ float bf2f(u16 h) {
  u32 u = ((u32)h) << 16;
  return __builtin_bit_cast(float, u);
}
__device__ __forceinline__ void gload_lds16(const void* g, void* l) {
  __builtin_amdgcn_global_load_lds((__attribute__((address_space(1))) void*)g,
                                   (__attribute__((address_space(3))) void*)l,
                                   16, 0, 0);
}

// ---------- cast+transpose W: wbt[n][k] = bf16(W[k][n]) ----------
__global__ __launch_bounds__(256) void k_cast_wT(const float* __restrict__ W, u16* __restrict__ wbt) {
  int idx = blockIdx.x * 256 + threadIdx.x;
  int k = idx >> 9, n = idx & 511;
  wbt[n * 512 + k] = f2bf(W[idx]);
}

// ---------- gemm1: h = x@W (M=16384,K=512,N=512). 128x128 tile, 4 waves.
// Triple-buffered, counted vmcnt, XCD-swizzled. Epilogue: hbf + score partials.
__global__ __launch_bounds__(256, 2) void k_gemm1(const float* __restrict__ x, const u16* __restrict__ wbt,
                                                  const float* __restrict__ a,
                                                  u16* __restrict__ hbf,
                                                  float* __restrict__ s1p, float* __restrict__ s2p) {
  __shared__ __attribute__((aligned(16))) char lds[73728];
  __shared__ __attribute__((aligned(16))) float a_l[256];

  const int t = threadIdx.x;
  const int lane = t & 63;
  const int w = t >> 6;
  const int l31 = lane & 31, lhi = lane >> 5;
  const int rb = w >> 1, cg = w & 1;
  const int g = blockIdx.x;
  const int cb = (g >> 3) & 3;
  const int tile_m = (g & 7) | ((g >> 5) << 3);
  const int row0 = tile_m * 128;
  const int col0 = cb * 128;

  a_l[t] = (t < 128) ? a[col0 + t] : a[512 + col0 + (t - 128)];

  f32x16 acc[2][2];
#pragma unroll
  for (int i = 0; i < 2; ++i)
#pragma unroll
    for (int j = 0; j < 2; ++j)
#pragma unroll
      for (int r = 0; r < 16; ++r) acc[i][j][r] = 0.f;

#define STAGE_G1(kt, Ab, Bb)                                                              \
  {                                                                                       \
    const int k0_ = (kt) * 32;                                                            \
    _Pragma("unroll")                                                                     \
    for (int i = 0; i < 4; ++i) {                                                         \
      int G = i * 256 + t;                                                                \
      int row = G >> 3, ks = G & 7;                                                       \
      gload_lds16(x + (size_t)(row0 + row) * 512 + k0_ + ((ks ^ (row & 7)) * 4),          \
                  (Ab) + (size_t)(i * 256 + w * 64) * 16);                                \
    }                                                                                     \
    _Pragma("unroll")                                                                     \
    for (int i = 0; i < 2; ++i) {                                                         \
      int G = i * 256 + t;                                                                \
      int col = G >> 2, ks = G & 3;                                                       \
      gload_lds16(wbt + (size_t)(col0 + col) * 512 + k0_ + ((ks ^ ((col >> 1) & 3)) * 8), \
                  (Bb) + (size_t)(i * 256 + w * 64) * 16);                                \
    }                                                                                     \
  }

#define COMPUTE_G1(Ab, Bb)                                                                         \
  {                                                                                                \
    _Pragma("unroll")                                                                              \
    for (int ks = 0; ks < 2; ++ks) {                                                               \
      bf16x8 af[2];                                                                                \
      _Pragma("unroll")                                                                            \
      for (int sub = 0; sub < 2; ++sub) {                                                          \
        const int arow = rb * 64 + sub * 32 + l31;                                                 \
        const int kg = ks * 4 + lhi * 2;                                                           \
        f32x4 fa0 = *reinterpret_cast<const f32x4*>((Ab) + (size_t)(arow * 8 + (kg ^ (arow & 7))) * 16); \
        f32x4 fa1 = *reinterpret_cast<const f32x4*>((Ab) + (size_t)(arow * 8 + ((kg + 1) ^ (arow & 7))) * 16); \
        _Pragma("unroll")                                                                          \
        for (int jj = 0; jj < 4; ++jj) {                                                           \
          af[sub][jj] = (__bf16)fa0[jj];                                                           \
          af[sub][jj + 4] = (__bf16)fa1[jj];                                                       \
        }                                                                                          \
      }                                                                                            \
      bf16x8 bfr[2];                                                                               \
      _Pragma("unroll")                                                                            \
      for (int bt = 0; bt < 2; ++bt) {                                                             \
        const int bcol = cg * 64 + bt * 32 + l31;                                                  \
        const int kslot = (ks * 2 + lhi) ^ ((bcol >> 1) & 3);                                      \
        bfr[bt] = *reinterpret_cast<const bf16x8*>((Bb) + (size_t)(bcol * 4 + kslot) * 16);        \
      }                                                                                            \
      _Pragma("unroll")                                                                            \
      for (int sub = 0; sub < 2; ++sub)                                                            \
        _Pragma("unroll")                                                                          \
        for (int bt = 0; bt < 2; ++bt)                                                             \
          acc[sub][bt] = __builtin_amdgcn_mfma_f32_32x32x16_bf16(af[sub], bfr[bt], acc[sub][bt], 0, 0, 0); \
    }                                                                                              \
  }

  char* Ac = lds;             char* Bc = lds + 49152;
  char* An = lds + 16384;     char* Bn = lds + 57344;
  char* As = lds + 32768;     char* Bs = lds + 65536;

  STAGE_G1(0, Ac, Bc);
  STAGE_G1(1, An, Bn);
  __builtin_amdgcn_sched_barrier(0);
  asm volatile("s_waitcnt vmcnt(6) lgkmcnt(0)" ::: "memory");
  __builtin_amdgcn_s_barrier();
  __builtin_amdgcn_sched_barrier(0);

#pragma unroll 1
  for (int kt = 0; kt < 14; ++kt) {
    STAGE_G1(kt + 2, As, Bs);
    COMPUTE_G1(Ac, Bc);
    __builtin_amdgcn_sched_barrier(0);
    asm volatile("s_waitcnt vmcnt(6)" ::: "memory");
    __builtin_amdgcn_s_barrier();
    __builtin_amdgcn_sched_barrier(0);
    char* ta = Ac; Ac = An; An = As; As = ta;
    char* tb = Bc; Bc = Bn; Bn = Bs; Bs = tb;
  }
  COMPUTE_G1(Ac, Bc);
  __builtin_amdgcn_sched_barrier(0);
  asm volatile("s_waitcnt vmcnt(0)" ::: "memory");
  __builtin_amdgcn_s_barrier();
  __builtin_amdgcn_sched_barrier(0);
  COMPUTE_G1(An, Bn);
#undef STAGE_G1
#undef COMPUTE_G1

  __syncthreads();

  u16* lT = (u16*)lds;
#pragma unroll
  for (int sub = 0; sub < 2; ++sub)
#pragma unroll
    for (int bt = 0; bt < 2; ++bt) {
      const int col = cg * 64 + bt * 32 + l31;
#pragma unroll
      for (int r = 0; r < 16; ++r) {
        int row = rb * 64 + sub * 32 + (r & 3) + 8 * (r >> 2) + 4 * lhi;
        lT[row * 136 + col] = f2bf(acc[sub][bt][r]);
      }
    }
  __syncthreads();

#pragma unroll
  for (int i = 0; i < 8; ++i) {
    int G = i * 256 + t;
    int row = G >> 4, gg = G & 15;
    uint4 v = *reinterpret_cast<const uint4*>(&lT[row * 136 + gg * 8]);
    *reinterpret_cast<uint4*>(&hbf[(size_t)(row0 + row) * 512 + col0 + gg * 8]) = v;
  }
  {
    const int r2 = t >> 1, half = t & 1;
    float d1 = 0.f, d2 = 0.f;
#pragma unroll
    for (int i = 0; i < 8; ++i) {
      uint4 v = *reinterpret_cast<const uint4*>(&lT[r2 * 136 + half * 64 + i * 8]);
      u32 wds[4] = {v.x, v.y, v.z, v.w};
#pragma unroll
      for (int jj = 0; jj < 8; ++jj) {
        float h = bf2f((u16)(wds[jj >> 1] >> ((jj & 1) * 16)));
        d1 += h * a_l[half * 64 + i * 8 + jj];
        d2 += h * a_l[128 + half * 64 + i * 8 + jj];
      }
    }
    d1 += __shfl_xor(d1, 1);
    d2 += __shfl_xor(d2, 1);
    if (half == 0) {
      s1p[cb * 16384 + row0 + r2] = d1;
      s2p[cb * 16384 + row0 + r2] = d2;
    }
  }
}

// ---------- prep: reduce partials; u32-key bitonic sort of s2L; E1/E2; scans ->
// exact denominators folded into c1i/c2i; kn. ----------
__global__ __launch_bounds__(1024) void k_prep(const float* __restrict__ s1p, const float* __restrict__ s2p,
                                               float* __restrict__ e1s, float* __restrict__ e2s,
                                               u32* __restrict__ permM, u32* __restrict__ kng,
                                               float* __restrict__ c1ig, float* __restrict__ c2ig) {
  __shared__ u32 sk[1024];
  __shared__ float s2all[1024];
  __shared__ float s2sv[1024];
  __shared__ float arrA[1024];
  __shared__ float arrB[1024];
  const int b = blockIdx.x;
  const int t = threadIdx.x;
  const int id = b * 1024 + t;

  const float s1v = (s1p[id] + s1p[16384 + id] + s1p[32768 + id] + s1p[49152 + id]) * LOG2E;
  const float s2v = (s2p[id] + s2p[16384 + id] + s2p[32768 + id] + s2p[49152 + id]) * LOG2E;
  s2all[t] = s2v;

  {
    u32 bits = __builtin_bit_cast(u32, s2v);
    u32 key = (bits & 0x80000000u) ? ~bits : (bits | 0x80000000u);
    sk[t] = (key & 0xFFFFFC00u) | (u32)t;   // truncated key | idx
  }
  for (int size = 2; size <= 1024; size <<= 1)
    for (int stride = size >> 1; stride > 0; stride >>= 1) {
      __syncthreads();
      int ixj = t ^ stride;
      if (ixj > t) {
        u32 va = sk[t], vb = sk[ixj];
        bool asc = ((t & size) == 0);
        if ((va > vb) == asc) { sk[t] = vb; sk[ixj] = va; }
      }
    }
  __syncthreads();

  const u32 idx = sk[t] & 1023u;
  const float sv = s2all[idx];
  s2sv[t] = sv;
  __syncthreads();

  const float E1 = exp2f(sv), E2 = exp2f(ALPHA * sv);
  e1s[b * 1024 + t] = E1;
  e2s[b * 1024 + t] = E2;
  permM[b * 1024 + t] = idx;
  arrA[t] = E2;
  arrB[t] = exp2f(s2sv[1023 - t]);
  __syncthreads();

  for (int off = 1; off < 1024; off <<= 1) {
    float aA = (t >= off) ? arrA[t - off] : 0.f;
    float aB = (t >= off) ? arrB[t - off] : 0.f;
    __syncthreads();
    arrA[t] += aA;
    arrB[t] += aB;
    __syncthreads();
  }

  {
    const float thr = -s1v;
    int lo = 0, hi = 1024;
    while (lo < hi) { int mid = (lo + hi) >> 1; if (s2sv[mid] <= thr) lo = mid + 1; else hi = mid; }
    const int kn = lo;
    float se1suf = (kn == 1024) ? 0.f : arrB[1023 - kn];
    float se2pre = (kn == 0) ? 0.f : arrA[kn - 1];
    const float c1 = exp2f(s1v), c2 = exp2f(ALPHA * s1v);
    const float inv = 1.0f / (c1 * se1suf + c2 * se2pre);
    c1ig[id] = c1 * inv;
    c2ig[id] = c2 * inv;
    kng[id] = (u32)kn;
  }
}

// ---------- sweep2: per (b, 16-f chunk): per-ELEMENT scan tables (no partials).
// Phase 1: gather 64 sorted h into packed regs; backward walk -> Cp1 (suffix e1·h),
// forward walk -> Cp2 (excl prefix e2·h), bf16 in LDS. Phase 2: pure lookups. ----------
__global__ __launch_bounds__(256, 2) void k_sweep2(const u16* __restrict__ hbf,
                                                   const float* __restrict__ e1s, const float* __restrict__ e2s,
                                                   const u32* __restrict__ permM, const u32* __restrict__ kng,
                                                   const float* __restrict__ c1ig, const float* __restrict__ c2ig,
                                                   const float* __restrict__ betag, float* __restrict__ out) {
  __shared__ u16 Cp1[1025][16];    // suffix incl: sum_{j>=i} e1·h  (bf16)
  __shared__ u16 Cp2[1025][16];    // prefix excl: sum_{j<i} e2·h   (bf16)
  __shared__ float c1i_l[1024];
  __shared__ float c2i_l[1024];
  __shared__ u16 kn_l[1024];
  __shared__ float segS1[16][16];
  __shared__ float segP2[16][16];

  const int t = threadIdx.x;
  const int B = blockIdx.x;
  const int b = (B & 7) * 2 + ((B >> 3) & 1);   // XCD swizzle: batch's 32 blocks share an XCD
  const int fc = B >> 4;                         // 0..31 : 16-f chunk

  const u16* hB = hbf + (size_t)b * 1024 * 512 + fc * 16;

#pragma unroll
  for (int q = 0; q < 4; ++q) {
    int i = q * 256 + t;
    c1i_l[i] = c1ig[b * 1024 + i];
    c2i_l[i] = c2ig[b * 1024 + i];
    kn_l[i] = (u16)kng[b * 1024 + i];
  }

  // phase 1: thread (seg=t>>4, f=t&15) owns sorted positions [seg*64, seg*64+64)
  const int f = t & 15;
  const int seg = t >> 4;
  const int i0 = seg * 64;
  const u32* permB = permM + b * 1024 + i0;
  const float* e1B = e1s + b * 1024 + i0;
  const float* e2B = e2s + b * 1024 + i0;

  // pass A: gather h (packed bf16 pairs in 32 regs) + totals
  u32 hpk[32];
  float ss1 = 0.f, ss2 = 0.f;
#pragma unroll 8
  for (int c = 0; c < 64; c += 2) {
    u16 h0 = hB[(size_t)permB[c] * 512 + f];
    u16 h1 = hB[(size_t)permB[c + 1] * 512 + f];
    hpk[c >> 1] = (u32)h0 | ((u32)h1 << 16);
    ss1 = fmaf(e1B[c], bf2f(h0), ss1);
    ss1 = fmaf(e1B[c + 1], bf2f(h1), ss1);
    ss2 = fmaf(e2B[c], bf2f(h0), ss2);
    ss2 = fmaf(e2B[c + 1], bf2f(h1), ss2);
  }
  segS1[seg][f] = ss1;
  segP2[seg][f] = ss2;
  __syncthreads();

  float sufAfter = 0.f, preBefore = 0.f;
#pragma unroll
  for (int s7 = 0; s7 < 16; ++s7) {
    if (s7 > seg) sufAfter += segS1[s7][f];
    if (s7 < seg) preBefore += segP2[s7][f];
  }

  // pass B: backward walk -> Cp1 (inclusive suffix at each index)
  if (seg == 15) Cp1[1024][f] = 0;
  {
    float run1 = sufAfter;
#pragma unroll
    for (int c = 63; c >= 0; --c) {
      u16 hv = (u16)((hpk[c >> 1] >> ((c & 1) * 16)) & 0xFFFFu);
      run1 = fmaf(e1B[c], bf2f(hv), run1);
      Cp1[i0 + c][f] = f2bf(run1);
    }
  }
  // pass C: forward walk -> Cp2 (exclusive prefix at each index)
  {
    float run2 = preBefore;
#pragma unroll
    for (int c = 0; c < 64; ++c) {
      Cp2[i0 + c][f] = f2bf(run2);
      u16 hv = (u16)((hpk[c >> 1] >> ((c & 1) * 16)) & 0xFFFFu);
      run2 = fmaf(e2B[c], bf2f(hv), run2);
    }
    if (seg == 15) Cp2[1024][f] = f2bf(run2);
  }
  __syncthreads();

  // phase 2: per row n: pure lookups + fused elu output (16 rows/iter, 64 iters)
  const float beta = betag[0];
  const int nl = t >> 4;
#pragma unroll 4
  for (int r = 0; r < 64; ++r) {
    const int n = r * 16 + nl;
    const int kn = kn_l[n];
    const float A = bf2f(Cp1[kn][f]);
    const float Bv = bf2f(Cp2[kn][f]);
    const float hvn = bf2f(hB[(size_t)n * 512 + f]);
    const float xv = c1i_l[n] * A + c2i_l[n] * Bv + beta * hvn;
    out[((size_t)b * 1024 + n) * 512 + fc * 16 + f] = xv > 0.f ? xv : __expf(xv) - 1.0f;
  }
}

extern "C" void kernel_launch(void* const* d_in, const int* in_sizes, int n_in,
                              void* d_out, int out_size, void* d_ws, size_t ws_size,
                              hipStream_t stream) {
  const float* x = (const float*)d_in[0];
  const float* W = (const float*)d_in[1];
  const float* a = (const float*)d_in[2];
  const float* beta = (const float*)d_in[3];
  float* out = (float*)d_out;

  char* ws = (char*)d_ws;
  u16* hbf = (u16*)ws;                                   // [0, 16M)
  char* sm = ws + (16u << 20);
  float* e1s = (float*)(sm);                             // 64 KB each
  float* e2s = (float*)(sm + (64u << 10));
  u32* permM = (u32*)(sm + (128u << 10));
  u32* kng = (u32*)(sm + (192u << 10));
  float* c1i = (float*)(sm + (256u << 10));
  float* c2i = (float*)(sm + (320u << 10));
  float* s1p = (float*)(sm + (512u << 10));              // 256 KB
  float* s2p = (float*)(sm + (768u << 10));              // 256 KB
  u16* wbt = (u16*)(sm + (1024u << 10));                 // 512 KB

  k_cast_wT<<<1024, 256, 0, stream>>>(W, wbt);
  k_gemm1<<<512, 256, 0, stream>>>(x, wbt, a, hbf, s1p, s2p);
  k_prep<<<16, 1024, 0, stream>>>(s1p, s2p, e1s, e2s, permM, kng, c1i, c2i);
  k_sweep2<<<512, 256, 0, stream>>>(hbf, e1s, e2s, permM, kng, c1i, c2i, beta, out);
}